// Round 1
// baseline (754.118 us; speedup 1.0000x reference)
//
#include <hip/hip_runtime.h>
#include <hip/hip_bf16.h>
#include <math.h>

// Problem constants (from setup_inputs):
#define NN 1024
#define TT 128
#define SS 6
#define FF 2
#define HH 256
#define G3 768
#define AA 18
#define MM 512
#define KH 20
#define BB (NN*SS)        // 6144
#define RR (FF*BB)        // 12288

typedef __bf16 bf16x8 __attribute__((ext_vector_type(8)));
typedef float f32x4 __attribute__((ext_vector_type(4)));

__device__ __forceinline__ f32x4 mfma16(bf16x8 a, bf16x8 b, f32x4 c) {
    return __builtin_amdgcn_mfma_f32_16x16x32_bf16(a, b, c, 0, 0, 0);
}

__device__ __forceinline__ unsigned short f2b(float f) {
    return __builtin_bit_cast(unsigned short, __float2bfloat16(f));
}

// ---- ws layout (bytes) ----
#define OFF_H32   0UL                 // B*H f32      = 6,291,456
#define OFF_HB    6291456UL           // B*H bf16     = 3,145,728
#define OFF_ACT   9437184UL           // 20*B int     =   491,520
#define OFF_HPRED 9928704UL           // R*H bf16     = 6,291,456
#define OFF_X1    16220160UL          // R*M bf16     = 12,582,912
#define OFF_X2    28803072UL          // R*M bf16     = 12,582,912
#define OFF_PRED  41385984UL          // R*H f32      = 12,582,912
#define OFF_WHH   53968896UL          // 768*256 bf16 =   393,216
#define OFF_W1T   54362112UL          // 512*256 bf16 =   262,144
#define OFF_W2T   54624256UL          // 512*512 bf16 =   524,288
#define OFF_W3T   55148544UL          // 256*512 bf16 =   262,144
#define OFF_SCAL  55410688UL          // 3 f32 accumulators

// Convert weights to bf16 (+ transpose W1,W2,W3 to [out][k]) and zero scalars.
__global__ void k_weights(const float* __restrict__ Whh, const float* __restrict__ W1,
                          const float* __restrict__ W2, const float* __restrict__ W3,
                          unsigned short* whh_b, unsigned short* w1t,
                          unsigned short* w2t, unsigned short* w3t, float* scal) {
    int idx = blockIdx.x * 256 + threadIdx.x;
    if (idx == 0) { scal[0] = 0.f; scal[1] = 0.f; scal[2] = 0.f; }
    if (idx < 196608) { whh_b[idx] = f2b(Whh[idx]); return; }
    idx -= 196608;
    if (idx < 131072) { int m = idx >> 8, k = idx & 255; w1t[idx] = f2b(W1[k * MM + m]); return; }
    idx -= 131072;
    if (idx < 262144) { int m = idx >> 9, k = idx & 511; w2t[idx] = f2b(W2[k * MM + m]); return; }
    idx -= 262144;
    { int c = idx >> 9, k = idx & 511; w3t[idx] = f2b(W3[k * HH + c]); }
}

// Gather h0 rows from b_t; build per-(step,row) action index (-1 => zero input).
__global__ void k_init(const float* __restrict__ b_t, const int* __restrict__ actions,
                       const int* __restrict__ ts, float* h32, unsigned short* hb, int* act) {
    int b = blockIdx.x, j = threadIdx.x;
    int n = b / SS, s = b - n * SS;
    int t = ts[s];
    float v = b_t[(size_t)(n * TT + t) * HH + j];
    h32[(size_t)b * HH + j] = v;
    hb[(size_t)b * HH + j] = f2b(v);
    if (j < KH) {
        int tt = t + j;
        act[j * BB + b] = (tt < TT - 1) ? actions[n * TT + tt] : -1;
    }
}

// One GRU step: gh = h_bf16 @ Whh^T (MFMA, fp32 acc), gates fused in-register.
// 192 blocks x 512 threads; block owns 32 rows; wave w owns j in [w*32, w*32+32).
__global__ void k_gru(const unsigned short* __restrict__ whh_b, const float* __restrict__ Wih,
                      const float* __restrict__ bih, const float* __restrict__ bhh,
                      const int* __restrict__ act, const int* __restrict__ us,
                      float* h32, unsigned short* hb, unsigned short* hpred, int ki) {
    int u0 = us[0], u1 = us[1];
    if (ki > (u0 > u1 ? u0 : u1)) return;   // deterministic early exit

    __shared__ alignas(16) unsigned short htile[32][264];   // +8 pad breaks bank conflicts
    int tid = threadIdx.x;
    int rb = blockIdx.x * 32;

    for (int c = tid; c < 1024; c += 512) {   // 32 rows x 32 chunks of 8 bf16
        int row = c >> 5, cc = (c & 31) << 3;
        *reinterpret_cast<uint4*>(&htile[row][cc]) =
            *reinterpret_cast<const uint4*>(&hb[(size_t)(rb + row) * HH + cc]);
    }
    __syncthreads();

    int wave = tid >> 6, lane = tid & 63;
    int l15 = lane & 15, lk8 = (lane >> 4) << 3;

    f32x4 acc[2][6] = {};   // [rowtile][gate*2+cj]
    for (int kk = 0; kk < 8; ++kk) {
        int k0 = kk * 32;
        bf16x8 a0 = *reinterpret_cast<const bf16x8*>(&htile[l15][k0 + lk8]);
        bf16x8 a1 = *reinterpret_cast<const bf16x8*>(&htile[16 + l15][k0 + lk8]);
#pragma unroll
        for (int ct = 0; ct < 6; ++ct) {
            int g = ct >> 1, cj = ct & 1;
            int wrow = g * 256 + wave * 32 + cj * 16 + l15;
            bf16x8 bf = *reinterpret_cast<const bf16x8*>(&whh_b[(size_t)wrow * HH + k0 + lk8]);
            acc[0][ct] = mfma16(a0, bf, acc[0][ct]);
            acc[1][ct] = mfma16(a1, bf, acc[1][ct]);
        }
    }

    int r4 = (lane >> 4) << 2;
#pragma unroll
    for (int rt = 0; rt < 2; ++rt)
#pragma unroll
        for (int cj = 0; cj < 2; ++cj)
#pragma unroll
            for (int reg = 0; reg < 4; ++reg) {
                int b = rb + rt * 16 + r4 + reg;
                int j = wave * 32 + cj * 16 + l15;
                float ghr = acc[rt][0 + cj][reg] + bhh[j];
                float ghz = acc[rt][2 + cj][reg] + bhh[256 + j];
                float ghn = acc[rt][4 + cj][reg] + bhh[512 + j];
                int a = act[ki * BB + b];
                float gir = bih[j], giz = bih[256 + j], gin = bih[512 + j];
                if (a >= 0) {
                    gir += Wih[j * AA + a];
                    giz += Wih[(256 + j) * AA + a];
                    gin += Wih[(512 + j) * AA + a];
                }
                float r = 1.f / (1.f + expf(-(gir + ghr)));
                float z = 1.f / (1.f + expf(-(giz + ghz)));
                float nn = tanhf(gin + r * ghn);
                size_t off = (size_t)b * HH + j;
                float hold = h32[off];
                float hnew = (1.f - z) * nn + z * hold;
                h32[off] = hnew;
                unsigned short hbv = f2b(hnew);
                hb[off] = hbv;
                if (ki == u0) hpred[off] = hbv;
                if (ki == u1) hpred[(size_t)BB * HH + off] = hbv;
            }
}

// Generic MLP GEMM: out[r][c] = act(A[r][:] . Bt[c][:] + bias[c]); 64x64 block tile.
template <bool RELU, bool WF32, bool WB16>
__global__ void k_mlp(const unsigned short* __restrict__ Abf, const unsigned short* __restrict__ Bt,
                      const float* __restrict__ bias, unsigned short* outB, float* outF,
                      int Kd, int Ncols) {
    int nb = Ncols >> 6;
    int br = blockIdx.x / nb, bc = blockIdx.x % nb;
    int tid = threadIdx.x, wave = tid >> 6, lane = tid & 63;
    int l15 = lane & 15, lk8 = (lane >> 4) << 3;
    int rb = br * 64 + (wave >> 1) * 32;
    int cb = bc * 64 + (wave & 1) * 32;
    f32x4 acc[2][2] = {};
    for (int k0 = 0; k0 < Kd; k0 += 32) {
        bf16x8 a0 = *reinterpret_cast<const bf16x8*>(&Abf[(size_t)(rb + l15) * Kd + k0 + lk8]);
        bf16x8 a1 = *reinterpret_cast<const bf16x8*>(&Abf[(size_t)(rb + 16 + l15) * Kd + k0 + lk8]);
        bf16x8 b0 = *reinterpret_cast<const bf16x8*>(&Bt[(size_t)(cb + l15) * Kd + k0 + lk8]);
        bf16x8 b1 = *reinterpret_cast<const bf16x8*>(&Bt[(size_t)(cb + 16 + l15) * Kd + k0 + lk8]);
        acc[0][0] = mfma16(a0, b0, acc[0][0]);
        acc[0][1] = mfma16(a0, b1, acc[0][1]);
        acc[1][0] = mfma16(a1, b0, acc[1][0]);
        acc[1][1] = mfma16(a1, b1, acc[1][1]);
    }
    int r4 = (lane >> 4) << 2;
#pragma unroll
    for (int rt = 0; rt < 2; ++rt)
#pragma unroll
        for (int ct = 0; ct < 2; ++ct)
#pragma unroll
            for (int reg = 0; reg < 4; ++reg) {
                int row = rb + rt * 16 + r4 + reg;
                int col = cb + ct * 16 + l15;
                float v = acc[rt][ct][reg] + bias[col];
                if (RELU) v = fmaxf(v, 0.f);
                if (WB16) outB[(size_t)row * Ncols + col] = f2b(v);
                if (WF32) outF[(size_t)row * Ncols + col] = v;
            }
}

// Per-row: reg term (all rows), masked normalized MSE (valid rows). One wave per row.
__global__ void k_loss(const float* __restrict__ pred, const float* __restrict__ z_t,
                       const float* __restrict__ dones, const int* __restrict__ ts,
                       const int* __restrict__ us, float* scal) {
    int wave = threadIdx.x >> 6, lane = threadIdx.x & 63;
    int row = blockIdx.x * 4 + wave;
    int f = row / BB, b = row - f * BB;
    int n = b / SS, s = b - n * SS;
    int t = ts[s], u = us[f];

    const float* pr = pred + (size_t)row * HH;
    float pv[4], ssq = 0.f;
#pragma unroll
    for (int i = 0; i < 4; ++i) { pv[i] = pr[lane + 64 * i]; ssq += pv[i] * pv[i]; }
    for (int o = 32; o; o >>= 1) ssq += __shfl_down(ssq, o);
    float norm = __shfl(sqrtf(ssq), 0);
    if (lane == 0) {
        float d = norm - 1.f;
        atomicAdd(&scal[2], 0.02f * d * d);
    }

    bool valid = (t + u) < (TT - 1);
    if (valid) {
        float m = 1.f;
        for (int jj = 0; jj <= u; ++jj) m *= (1.f - dones[n * TT + t + jj]);
        valid = (m > 0.f);
    }
    if (!valid) return;

    const float* zr = z_t + (size_t)(n * TT + 1 + t + u) * HH;
    float zv[4], zsq = 0.f;
#pragma unroll
    for (int i = 0; i < 4; ++i) { zv[i] = zr[lane + 64 * i]; zsq += zv[i] * zv[i]; }
    for (int o = 32; o; o >>= 1) zsq += __shfl_down(zsq, o);
    float tn = __shfl(sqrtf(zsq), 0);

    float ip = 1.f / fmaxf(norm, 1e-8f);
    float it = 1.f / fmaxf(tn, 1e-8f);
    float e = 0.f;
#pragma unroll
    for (int i = 0; i < 4; ++i) { float d = pv[i] * ip - zv[i] * it; e += d * d; }
    for (int o = 32; o; o >>= 1) e += __shfl_down(e, o);
    if (lane == 0) {
        atomicAdd(&scal[0], e * (1.f / HH));
        atomicAdd(&scal[1], 1.f);
    }
}

__global__ void k_final(const float* __restrict__ scal, float* out) {
    out[0] = scal[0] / fmaxf(scal[1], 1.f) + scal[2] * (1.f / RR);
}

extern "C" void kernel_launch(void* const* d_in, const int* in_sizes, int n_in,
                              void* d_out, int out_size, void* d_ws, size_t ws_size,
                              hipStream_t stream) {
    const int*   actions = (const int*)d_in[0];
    const float* dones   = (const float*)d_in[1];
    const float* b_t     = (const float*)d_in[2];
    const float* z_t     = (const float*)d_in[3];
    const int*   ts      = (const int*)d_in[4];
    const int*   us      = (const int*)d_in[5];
    const float* W_ih    = (const float*)d_in[6];
    const float* W_hh    = (const float*)d_in[7];
    const float* b_ih    = (const float*)d_in[8];
    const float* b_hh    = (const float*)d_in[9];
    const float* W1      = (const float*)d_in[10];
    const float* b1      = (const float*)d_in[11];
    const float* W2      = (const float*)d_in[12];
    const float* b2      = (const float*)d_in[13];
    const float* W3      = (const float*)d_in[14];
    const float* b3      = (const float*)d_in[15];

    char* ws = (char*)d_ws;
    float*          h32   = (float*)(ws + OFF_H32);
    unsigned short* hb    = (unsigned short*)(ws + OFF_HB);
    int*            act   = (int*)(ws + OFF_ACT);
    unsigned short* hpred = (unsigned short*)(ws + OFF_HPRED);
    unsigned short* x1    = (unsigned short*)(ws + OFF_X1);
    unsigned short* x2    = (unsigned short*)(ws + OFF_X2);
    float*          pred  = (float*)(ws + OFF_PRED);
    unsigned short* whh_b = (unsigned short*)(ws + OFF_WHH);
    unsigned short* w1t   = (unsigned short*)(ws + OFF_W1T);
    unsigned short* w2t   = (unsigned short*)(ws + OFF_W2T);
    unsigned short* w3t   = (unsigned short*)(ws + OFF_W3T);
    float*          scal  = (float*)(ws + OFF_SCAL);

    k_weights<<<2816, 256, 0, stream>>>(W_hh, W1, W2, W3, whh_b, w1t, w2t, w3t, scal);
    k_init<<<BB, 256, 0, stream>>>(b_t, actions, ts, h32, hb, act);
    for (int ki = 0; ki < KH; ++ki)
        k_gru<<<192, 512, 0, stream>>>(whh_b, W_ih, b_ih, b_hh, act, us, h32, hb, hpred, ki);
    k_mlp<true,  false, true ><<<(RR / 64) * (MM / 64), 256, 0, stream>>>(hpred, w1t, b1, x1, nullptr, HH, MM);
    k_mlp<true,  false, true ><<<(RR / 64) * (MM / 64), 256, 0, stream>>>(x1, w2t, b2, x2, nullptr, MM, MM);
    k_mlp<false, true,  false><<<(RR / 64) * (HH / 64), 256, 0, stream>>>(x2, w3t, b3, nullptr, pred, MM, HH);
    k_loss<<<RR / 4, 256, 0, stream>>>(pred, z_t, dones, ts, us, scal);
    k_final<<<1, 1, 0, stream>>>(scal, (float*)d_out);
}

// Round 2
// 290.728 us; speedup vs baseline: 2.5939x; 2.5939x over previous
//
#include <hip/hip_runtime.h>
#include <hip/hip_bf16.h>
#include <math.h>

// Problem constants (from setup_inputs):
#define NN 1024
#define TT 128
#define SS 6
#define FF 2
#define HH 256
#define G3 768
#define AA 18
#define MM 512
#define KH 20
#define BB (NN*SS)        // 6144
#define RR (FF*BB)        // 12288
#define LOSS_BLOCKS 1024

typedef __bf16 bf16x8 __attribute__((ext_vector_type(8)));
typedef float f32x4 __attribute__((ext_vector_type(4)));

__device__ __forceinline__ f32x4 mfma16(bf16x8 a, bf16x8 b, f32x4 c) {
    return __builtin_amdgcn_mfma_f32_16x16x32_bf16(a, b, c, 0, 0, 0);
}

__device__ __forceinline__ unsigned short f2b(float f) {
    return __builtin_bit_cast(unsigned short, __float2bfloat16(f));
}

// ---- ws layout (bytes) ----
#define OFF_H32   0UL                 // B*H f32      = 6,291,456
#define OFF_HB    6291456UL           // B*H bf16     = 3,145,728
#define OFF_ACT   9437184UL           // 20*B int     =   491,520
#define OFF_HPRED 9928704UL           // R*H bf16     = 6,291,456
#define OFF_X1    16220160UL          // R*M bf16     = 12,582,912
#define OFF_X2    28803072UL          // R*M bf16     = 12,582,912
#define OFF_PRED  41385984UL          // R*H f32      = 12,582,912
#define OFF_WHH   53968896UL          // 768*256 bf16 =   393,216
#define OFF_W1T   54362112UL          // 512*256 bf16 =   262,144
#define OFF_W2T   54624256UL          // 512*512 bf16 =   524,288
#define OFF_W3T   55148544UL          // 256*512 bf16 =   262,144
#define OFF_PART  55410688UL          // LOSS_BLOCKS*3 f32 partials = 12,288

// Convert weights to bf16 (+ transpose W1,W2,W3 to [out][k]).
__global__ void k_weights(const float* __restrict__ Whh, const float* __restrict__ W1,
                          const float* __restrict__ W2, const float* __restrict__ W3,
                          unsigned short* whh_b, unsigned short* w1t,
                          unsigned short* w2t, unsigned short* w3t) {
    int idx = blockIdx.x * 256 + threadIdx.x;
    if (idx < 196608) { whh_b[idx] = f2b(Whh[idx]); return; }
    idx -= 196608;
    if (idx < 131072) { int m = idx >> 8, k = idx & 255; w1t[idx] = f2b(W1[k * MM + m]); return; }
    idx -= 131072;
    if (idx < 262144) { int m = idx >> 9, k = idx & 511; w2t[idx] = f2b(W2[k * MM + m]); return; }
    idx -= 262144;
    { int c = idx >> 9, k = idx & 511; w3t[idx] = f2b(W3[k * HH + c]); }
}

// Gather h0 rows from b_t; build per-(step,row) action index (-1 => zero input).
__global__ void k_init(const float* __restrict__ b_t, const int* __restrict__ actions,
                       const int* __restrict__ ts, float* h32, unsigned short* hb, int* act) {
    int b = blockIdx.x, j = threadIdx.x;
    int n = b / SS, s = b - n * SS;
    int t = ts[s];
    float v = b_t[(size_t)(n * TT + t) * HH + j];
    h32[(size_t)b * HH + j] = v;
    hb[(size_t)b * HH + j] = f2b(v);
    if (j < KH) {
        int tt = t + j;
        act[j * BB + b] = (tt < TT - 1) ? actions[n * TT + tt] : -1;
    }
}

// One GRU step: gh = h_bf16 @ Whh^T (MFMA, fp32 acc), gates fused in-register.
// 192 blocks x 512 threads; block owns 32 rows; wave w owns j in [w*32, w*32+32).
__global__ void k_gru(const unsigned short* __restrict__ whh_b, const float* __restrict__ Wih,
                      const float* __restrict__ bih, const float* __restrict__ bhh,
                      const int* __restrict__ act, const int* __restrict__ us,
                      float* h32, unsigned short* hb, unsigned short* hpred, int ki) {
    int u0 = us[0], u1 = us[1];
    if (ki > (u0 > u1 ? u0 : u1)) return;   // deterministic early exit

    __shared__ alignas(16) unsigned short htile[32][264];   // +8 pad breaks bank conflicts
    int tid = threadIdx.x;
    int rb = blockIdx.x * 32;

    for (int c = tid; c < 1024; c += 512) {   // 32 rows x 32 chunks of 8 bf16
        int row = c >> 5, cc = (c & 31) << 3;
        *reinterpret_cast<uint4*>(&htile[row][cc]) =
            *reinterpret_cast<const uint4*>(&hb[(size_t)(rb + row) * HH + cc]);
    }
    __syncthreads();

    int wave = tid >> 6, lane = tid & 63;
    int l15 = lane & 15, lk8 = (lane >> 4) << 3;

    f32x4 acc[2][6] = {};   // [rowtile][gate*2+cj]
    for (int kk = 0; kk < 8; ++kk) {
        int k0 = kk * 32;
        bf16x8 a0 = *reinterpret_cast<const bf16x8*>(&htile[l15][k0 + lk8]);
        bf16x8 a1 = *reinterpret_cast<const bf16x8*>(&htile[16 + l15][k0 + lk8]);
#pragma unroll
        for (int ct = 0; ct < 6; ++ct) {
            int g = ct >> 1, cj = ct & 1;
            int wrow = g * 256 + wave * 32 + cj * 16 + l15;
            bf16x8 bf = *reinterpret_cast<const bf16x8*>(&whh_b[(size_t)wrow * HH + k0 + lk8]);
            acc[0][ct] = mfma16(a0, bf, acc[0][ct]);
            acc[1][ct] = mfma16(a1, bf, acc[1][ct]);
        }
    }

    int r4 = (lane >> 4) << 2;
#pragma unroll
    for (int rt = 0; rt < 2; ++rt)
#pragma unroll
        for (int cj = 0; cj < 2; ++cj)
#pragma unroll
            for (int reg = 0; reg < 4; ++reg) {
                int b = rb + rt * 16 + r4 + reg;
                int j = wave * 32 + cj * 16 + l15;
                float ghr = acc[rt][0 + cj][reg] + bhh[j];
                float ghz = acc[rt][2 + cj][reg] + bhh[256 + j];
                float ghn = acc[rt][4 + cj][reg] + bhh[512 + j];
                int a = act[ki * BB + b];
                float gir = bih[j], giz = bih[256 + j], gin = bih[512 + j];
                if (a >= 0) {
                    gir += Wih[j * AA + a];
                    giz += Wih[(256 + j) * AA + a];
                    gin += Wih[(512 + j) * AA + a];
                }
                float r = 1.f / (1.f + expf(-(gir + ghr)));
                float z = 1.f / (1.f + expf(-(giz + ghz)));
                float nn = tanhf(gin + r * ghn);
                size_t off = (size_t)b * HH + j;
                float hold = h32[off];
                float hnew = (1.f - z) * nn + z * hold;
                h32[off] = hnew;
                unsigned short hbv = f2b(hnew);
                hb[off] = hbv;
                if (ki == u0) hpred[off] = hbv;
                if (ki == u1) hpred[(size_t)BB * HH + off] = hbv;
            }
}

// Generic MLP GEMM: out[r][c] = act(A[r][:] . Bt[c][:] + bias[c]); 64x64 block tile.
template <bool RELU, bool WF32, bool WB16>
__global__ void k_mlp(const unsigned short* __restrict__ Abf, const unsigned short* __restrict__ Bt,
                      const float* __restrict__ bias, unsigned short* outB, float* outF,
                      int Kd, int Ncols) {
    int nb = Ncols >> 6;
    int br = blockIdx.x / nb, bc = blockIdx.x % nb;
    int tid = threadIdx.x, wave = tid >> 6, lane = tid & 63;
    int l15 = lane & 15, lk8 = (lane >> 4) << 3;
    int rb = br * 64 + (wave >> 1) * 32;
    int cb = bc * 64 + (wave & 1) * 32;
    f32x4 acc[2][2] = {};
    for (int k0 = 0; k0 < Kd; k0 += 32) {
        bf16x8 a0 = *reinterpret_cast<const bf16x8*>(&Abf[(size_t)(rb + l15) * Kd + k0 + lk8]);
        bf16x8 a1 = *reinterpret_cast<const bf16x8*>(&Abf[(size_t)(rb + 16 + l15) * Kd + k0 + lk8]);
        bf16x8 b0 = *reinterpret_cast<const bf16x8*>(&Bt[(size_t)(cb + l15) * Kd + k0 + lk8]);
        bf16x8 b1 = *reinterpret_cast<const bf16x8*>(&Bt[(size_t)(cb + 16 + l15) * Kd + k0 + lk8]);
        acc[0][0] = mfma16(a0, b0, acc[0][0]);
        acc[0][1] = mfma16(a0, b1, acc[0][1]);
        acc[1][0] = mfma16(a1, b0, acc[1][0]);
        acc[1][1] = mfma16(a1, b1, acc[1][1]);
    }
    int r4 = (lane >> 4) << 2;
#pragma unroll
    for (int rt = 0; rt < 2; ++rt)
#pragma unroll
        for (int ct = 0; ct < 2; ++ct)
#pragma unroll
            for (int reg = 0; reg < 4; ++reg) {
                int row = rb + rt * 16 + r4 + reg;
                int col = cb + ct * 16 + l15;
                float v = acc[rt][ct][reg] + bias[col];
                if (RELU) v = fmaxf(v, 0.f);
                if (WB16) outB[(size_t)row * Ncols + col] = f2b(v);
                if (WF32) outF[(size_t)row * Ncols + col] = v;
            }
}

// Per-row: reg term (all rows), masked normalized MSE (valid rows).
// LOSS_BLOCKS blocks x 256 threads (4 waves); block owns 12 rows, wave owns 3.
// Deterministic two-stage reduction: block partials -> ws, no atomics.
__global__ void k_loss(const float* __restrict__ pred, const float* __restrict__ z_t,
                       const float* __restrict__ dones, const int* __restrict__ ts,
                       const int* __restrict__ us, float* part) {
    int wave = threadIdx.x >> 6, lane = threadIdx.x & 63;
    float mse_l = 0.f;           // lane-partial, butterfly-reduced at end
    float cnt_l = 0.f, reg_l = 0.f;  // lane-0-only accumulators

    for (int i = 0; i < 3; ++i) {
        int row = blockIdx.x * 12 + wave * 3 + i;
        int f = row / BB, b = row - f * BB;
        int n = b / SS, s = b - n * SS;
        int t = ts[s], u = us[f];

        const float* pr = pred + (size_t)row * HH;
        float pv[4], ssq = 0.f;
#pragma unroll
        for (int q = 0; q < 4; ++q) { pv[q] = pr[lane + 64 * q]; ssq += pv[q] * pv[q]; }
        for (int o = 32; o; o >>= 1) ssq += __shfl_xor(ssq, o);
        float norm = sqrtf(ssq);
        if (lane == 0) { float d = norm - 1.f; reg_l += 0.02f * d * d; }

        bool valid = (t + u) < (TT - 1);
        if (valid) {
            float m = 1.f;
            for (int jj = 0; jj <= u; ++jj) m *= (1.f - dones[n * TT + t + jj]);
            valid = (m > 0.f);
        }
        if (!valid) continue;

        const float* zr = z_t + (size_t)(n * TT + 1 + t + u) * HH;
        float zv[4], zsq = 0.f;
#pragma unroll
        for (int q = 0; q < 4; ++q) { zv[q] = zr[lane + 64 * q]; zsq += zv[q] * zv[q]; }
        for (int o = 32; o; o >>= 1) zsq += __shfl_xor(zsq, o);
        float tn = sqrtf(zsq);

        float ip = 1.f / fmaxf(norm, 1e-8f);
        float it = 1.f / fmaxf(tn, 1e-8f);
        float e = 0.f;
#pragma unroll
        for (int q = 0; q < 4; ++q) { float d = pv[q] * ip - zv[q] * it; e += d * d; }
        mse_l += e * (1.f / HH);
        if (lane == 0) cnt_l += 1.f;
    }

    for (int o = 32; o; o >>= 1) mse_l += __shfl_xor(mse_l, o);

    __shared__ float sm[4][3];
    if (lane == 0) { sm[wave][0] = mse_l; sm[wave][1] = cnt_l; sm[wave][2] = reg_l; }
    __syncthreads();
    if (threadIdx.x == 0) {
        float s0 = 0.f, s1 = 0.f, s2 = 0.f;
        for (int w = 0; w < 4; ++w) { s0 += sm[w][0]; s1 += sm[w][1]; s2 += sm[w][2]; }
        part[blockIdx.x * 3 + 0] = s0;
        part[blockIdx.x * 3 + 1] = s1;
        part[blockIdx.x * 3 + 2] = s2;
    }
}

// Single-block final reduction over LOSS_BLOCKS partials.
__global__ void k_final(const float* __restrict__ part, float* out) {
    int tid = threadIdx.x, wave = tid >> 6, lane = tid & 63;
    float s0 = 0.f, s1 = 0.f, s2 = 0.f;
    for (int i = tid; i < LOSS_BLOCKS; i += 256) {
        s0 += part[i * 3 + 0];
        s1 += part[i * 3 + 1];
        s2 += part[i * 3 + 2];
    }
    for (int o = 32; o; o >>= 1) {
        s0 += __shfl_xor(s0, o);
        s1 += __shfl_xor(s1, o);
        s2 += __shfl_xor(s2, o);
    }
    __shared__ float sm[4][3];
    if (lane == 0) { sm[wave][0] = s0; sm[wave][1] = s1; sm[wave][2] = s2; }
    __syncthreads();
    if (tid == 0) {
        float a = 0.f, b = 0.f, c = 0.f;
        for (int w = 0; w < 4; ++w) { a += sm[w][0]; b += sm[w][1]; c += sm[w][2]; }
        out[0] = a / fmaxf(b, 1.f) + c * (1.f / RR);
    }
}

extern "C" void kernel_launch(void* const* d_in, const int* in_sizes, int n_in,
                              void* d_out, int out_size, void* d_ws, size_t ws_size,
                              hipStream_t stream) {
    const int*   actions = (const int*)d_in[0];
    const float* dones   = (const float*)d_in[1];
    const float* b_t     = (const float*)d_in[2];
    const float* z_t     = (const float*)d_in[3];
    const int*   ts      = (const int*)d_in[4];
    const int*   us      = (const int*)d_in[5];
    const float* W_ih    = (const float*)d_in[6];
    const float* W_hh    = (const float*)d_in[7];
    const float* b_ih    = (const float*)d_in[8];
    const float* b_hh    = (const float*)d_in[9];
    const float* W1      = (const float*)d_in[10];
    const float* b1      = (const float*)d_in[11];
    const float* W2      = (const float*)d_in[12];
    const float* b2      = (const float*)d_in[13];
    const float* W3      = (const float*)d_in[14];
    const float* b3      = (const float*)d_in[15];

    char* ws = (char*)d_ws;
    float*          h32   = (float*)(ws + OFF_H32);
    unsigned short* hb    = (unsigned short*)(ws + OFF_HB);
    int*            act   = (int*)(ws + OFF_ACT);
    unsigned short* hpred = (unsigned short*)(ws + OFF_HPRED);
    unsigned short* x1    = (unsigned short*)(ws + OFF_X1);
    unsigned short* x2    = (unsigned short*)(ws + OFF_X2);
    float*          pred  = (float*)(ws + OFF_PRED);
    unsigned short* whh_b = (unsigned short*)(ws + OFF_WHH);
    unsigned short* w1t   = (unsigned short*)(ws + OFF_W1T);
    unsigned short* w2t   = (unsigned short*)(ws + OFF_W2T);
    unsigned short* w3t   = (unsigned short*)(ws + OFF_W3T);
    float*          part  = (float*)(ws + OFF_PART);

    k_weights<<<2816, 256, 0, stream>>>(W_hh, W1, W2, W3, whh_b, w1t, w2t, w3t);
    k_init<<<BB, 256, 0, stream>>>(b_t, actions, ts, h32, hb, act);
    for (int ki = 0; ki < KH; ++ki)
        k_gru<<<192, 512, 0, stream>>>(whh_b, W_ih, b_ih, b_hh, act, us, h32, hb, hpred, ki);
    k_mlp<true,  false, true ><<<(RR / 64) * (MM / 64), 256, 0, stream>>>(hpred, w1t, b1, x1, nullptr, HH, MM);
    k_mlp<true,  false, true ><<<(RR / 64) * (MM / 64), 256, 0, stream>>>(x1, w2t, b2, x2, nullptr, MM, MM);
    k_mlp<false, true,  false><<<(RR / 64) * (HH / 64), 256, 0, stream>>>(x2, w3t, b3, nullptr, pred, MM, HH);
    k_loss<<<LOSS_BLOCKS, 256, 0, stream>>>(pred, z_t, dones, ts, us, part);
    k_final<<<1, 256, 0, stream>>>(part, (float*)d_out);
}

// Round 3
// 197.243 us; speedup vs baseline: 3.8233x; 1.4740x over previous
//
#include <hip/hip_runtime.h>
#include <hip/hip_bf16.h>
#include <math.h>

// Problem constants (from setup_inputs):
#define NN 1024
#define TT 128
#define SS 6
#define FF 2
#define HH 256
#define AA 18
#define MM 512
#define KH 20
#define BB (NN*SS)        // 6144
#define RR (FF*BB)        // 12288
#define LOSS_BLOCKS 1024

typedef __bf16 bf16x8 __attribute__((ext_vector_type(8)));
typedef float f32x4 __attribute__((ext_vector_type(4)));

__device__ __forceinline__ f32x4 mfma16(bf16x8 a, bf16x8 b, f32x4 c) {
    return __builtin_amdgcn_mfma_f32_16x16x32_bf16(a, b, c, 0, 0, 0);
}
__device__ __forceinline__ unsigned short f2b(float f) {
    return __builtin_bit_cast(unsigned short, __float2bfloat16(f));
}
__device__ __forceinline__ float rcp_f(float x) { return __builtin_amdgcn_rcpf(x); }

// ---- ws layout (bytes) ----
#define OFF_ACT   0UL                 // 20*B int          =   491,520
#define OFF_HPRED 491520UL            // R*H bf16          = 6,291,456
#define OFF_PRED  6782976UL           // R*H f32           = 12,582,912
#define OFF_WHH   19365888UL          // 768*256 bf16      =   393,216
#define OFF_W1T   19759104UL          // 512*256 bf16      =   262,144
#define OFF_W2T   20021248UL          // 512*512 bf16      =   524,288
#define OFF_W3T   20545536UL          // 256*512 bf16      =   262,144
#define OFF_WIHP  20807680UL          // 768*32 bf16       =    49,152
#define OFF_PART  20856832UL          // LOSS_BLOCKS*3 f32 =    12,288

// Prep: weight bf16 conversion (+transposes), wih_pad (Wih | bias ones-col), act table.
__global__ void k_prep(const float* __restrict__ Whh, const float* __restrict__ W1,
                       const float* __restrict__ W2, const float* __restrict__ W3,
                       const float* __restrict__ Wih, const float* __restrict__ bih,
                       const float* __restrict__ bhh,
                       const int* __restrict__ actions, const int* __restrict__ ts,
                       unsigned short* whh_b, unsigned short* w1t, unsigned short* w2t,
                       unsigned short* w3t, unsigned short* wihp, int* act) {
    int idx = blockIdx.x * 256 + threadIdx.x;
    if (idx < 196608) { whh_b[idx] = f2b(Whh[idx]); return; }
    idx -= 196608;
    if (idx < 131072) { int m = idx >> 8, k = idx & 255; w1t[idx] = f2b(W1[k * MM + m]); return; }
    idx -= 131072;
    if (idx < 262144) { int m = idx >> 9, k = idx & 511; w2t[idx] = f2b(W2[k * MM + m]); return; }
    idx -= 262144;
    if (idx < 131072) { int c = idx >> 9, k = idx & 511; w3t[idx] = f2b(W3[k * HH + c]); return; }
    idx -= 131072;
    if (idx < 24576) {
        int c = idx >> 5, k = idx & 31;
        float v = 0.f;
        if (k < AA) v = Wih[c * AA + k];
        else if (k == AA) v = bih[c] + (c < 512 ? bhh[c] : 0.f);  // ones-col: bih (+bhh for r,z)
        wihp[idx] = f2b(v);
        return;
    }
    idx -= 24576;
    {   // act[ki][b]
        int ki = idx / BB, b = idx - ki * BB;
        int n = b / SS, s = b - n * SS;
        int tt = ts[s] + ki;
        act[idx] = (tt < TT - 1) ? actions[n * TT + tt] : -1;
    }
}

// Persistent GRU: 128 blocks x 512 thr; block owns 48 rows for all <=20 steps.
// h fp32 master in registers; bf16 h exchanged via LDS; gi via one-hot MFMA.
__global__ void __launch_bounds__(512, 2)
k_gru_all(const unsigned short* __restrict__ whh, const unsigned short* __restrict__ wihp,
          const float* __restrict__ bhh, const int* __restrict__ act,
          const int* __restrict__ us, const int* __restrict__ ts,
          const float* __restrict__ b_t, unsigned short* __restrict__ hpred) {
    __shared__ unsigned short htile[48][264];
    __shared__ unsigned short oh[48][40];

    int tid = threadIdx.x, wave = tid >> 6, lane = tid & 63;
    int l15 = lane & 15, grp = lane >> 4, lk8 = grp << 3, r4 = grp << 2;
    int rb = blockIdx.x * 48;
    int u0 = us[0], u1 = us[1];
    int kmax = u0 > u1 ? u0 : u1;

    // persistent fp32 h master: lane owns rows rt*16+r4+reg, cols wave*32+cj*16+l15
    float hm[3][2][4];
#pragma unroll
    for (int rt = 0; rt < 3; ++rt)
#pragma unroll
        for (int cj = 0; cj < 2; ++cj)
#pragma unroll
            for (int reg = 0; reg < 4; ++reg) {
                int b = rb + rt * 16 + r4 + reg;
                int n = b / SS, s = b - n * SS;
                int t = ts[s];
                hm[rt][cj][reg] = b_t[(size_t)(n * TT + t) * HH + wave * 32 + cj * 16 + l15];
            }
    float bhn[2];
#pragma unroll
    for (int cj = 0; cj < 2; ++cj) bhn[cj] = bhh[512 + wave * 32 + cj * 16 + l15];

    // initial htile = bf16(h0)
    for (int i = tid; i < 48 * 32; i += 512) {
        int row = i >> 5, c8 = (i & 31) << 3;
        int b = rb + row;
        int n = b / SS, s = b - n * SS;
        const float* src = &b_t[(size_t)(n * TT + ts[s]) * HH + c8];
        uint4 pk;
        pk.x = f2b(src[0]) | ((unsigned)f2b(src[1]) << 16);
        pk.y = f2b(src[2]) | ((unsigned)f2b(src[3]) << 16);
        pk.z = f2b(src[4]) | ((unsigned)f2b(src[5]) << 16);
        pk.w = f2b(src[6]) | ((unsigned)f2b(src[7]) << 16);
        *reinterpret_cast<uint4*>(&htile[row][c8]) = pk;
    }

    for (int ki = 0; ki <= kmax; ++ki) {
        // build one-hot tile (k==a -> 1, k==18 -> 1 always; else 0)
        for (int i = tid; i < 48 * 20; i += 512) {
            int row = i / 20, m = i - row * 20;
            int a = act[ki * BB + rb + row];
            int k0 = m << 1, k1 = k0 + 1;
            unsigned v0 = (k0 == a || k0 == AA) ? 0x3F80u : 0u;
            unsigned v1 = (k1 == a || k1 == AA) ? 0x3F80u : 0u;
            *reinterpret_cast<unsigned*>(&oh[row][k0]) = v0 | (v1 << 16);
        }
        __syncthreads();   // htile + oh ready

        f32x4 aRZ[3][4] = {};   // r (cj 0,1), z (cj 2,3): gi+gh combined
        f32x4 aN[3][2]  = {};   // n gate, gh part
        f32x4 aNI[3][2] = {};   // n gate, gi part

        // gi = onehot @ wih_pad^T  (K=32)
        {
            bf16x8 ao0 = *reinterpret_cast<const bf16x8*>(&oh[l15][lk8]);
            bf16x8 ao1 = *reinterpret_cast<const bf16x8*>(&oh[16 + l15][lk8]);
            bf16x8 ao2 = *reinterpret_cast<const bf16x8*>(&oh[32 + l15][lk8]);
#pragma unroll
            for (int g = 0; g < 3; ++g)
#pragma unroll
                for (int cj = 0; cj < 2; ++cj) {
                    int wrow = g * 256 + wave * 32 + cj * 16 + l15;
                    bf16x8 bo = *reinterpret_cast<const bf16x8*>(&wihp[wrow * 32 + lk8]);
                    if (g == 0) {
                        aRZ[0][cj] = mfma16(ao0, bo, aRZ[0][cj]);
                        aRZ[1][cj] = mfma16(ao1, bo, aRZ[1][cj]);
                        aRZ[2][cj] = mfma16(ao2, bo, aRZ[2][cj]);
                    } else if (g == 1) {
                        aRZ[0][2 + cj] = mfma16(ao0, bo, aRZ[0][2 + cj]);
                        aRZ[1][2 + cj] = mfma16(ao1, bo, aRZ[1][2 + cj]);
                        aRZ[2][2 + cj] = mfma16(ao2, bo, aRZ[2][2 + cj]);
                    } else {
                        aNI[0][cj] = mfma16(ao0, bo, aNI[0][cj]);
                        aNI[1][cj] = mfma16(ao1, bo, aNI[1][cj]);
                        aNI[2][cj] = mfma16(ao2, bo, aNI[2][cj]);
                    }
                }
        }
        // gh = h @ Whh^T  (K=256)
        for (int kk = 0; kk < 8; ++kk) {
            int k0 = kk * 32 + lk8;
            bf16x8 ah0 = *reinterpret_cast<const bf16x8*>(&htile[l15][k0]);
            bf16x8 ah1 = *reinterpret_cast<const bf16x8*>(&htile[16 + l15][k0]);
            bf16x8 ah2 = *reinterpret_cast<const bf16x8*>(&htile[32 + l15][k0]);
#pragma unroll
            for (int g = 0; g < 3; ++g)
#pragma unroll
                for (int cj = 0; cj < 2; ++cj) {
                    int wrow = g * 256 + wave * 32 + cj * 16 + l15;
                    bf16x8 bw = *reinterpret_cast<const bf16x8*>(&whh[(size_t)wrow * HH + k0]);
                    if (g == 0) {
                        aRZ[0][cj] = mfma16(ah0, bw, aRZ[0][cj]);
                        aRZ[1][cj] = mfma16(ah1, bw, aRZ[1][cj]);
                        aRZ[2][cj] = mfma16(ah2, bw, aRZ[2][cj]);
                    } else if (g == 1) {
                        aRZ[0][2 + cj] = mfma16(ah0, bw, aRZ[0][2 + cj]);
                        aRZ[1][2 + cj] = mfma16(ah1, bw, aRZ[1][2 + cj]);
                        aRZ[2][2 + cj] = mfma16(ah2, bw, aRZ[2][2 + cj]);
                    } else {
                        aN[0][cj] = mfma16(ah0, bw, aN[0][cj]);
                        aN[1][cj] = mfma16(ah1, bw, aN[1][cj]);
                        aN[2][cj] = mfma16(ah2, bw, aN[2][cj]);
                    }
                }
        }
        __syncthreads();   // all LDS reads done before epilogue writes

        // gates + state update (biases for r,z folded into wih_pad ones-col)
#pragma unroll
        for (int rt = 0; rt < 3; ++rt)
#pragma unroll
            for (int cj = 0; cj < 2; ++cj)
#pragma unroll
                for (int reg = 0; reg < 4; ++reg) {
                    int rl = rt * 16 + r4 + reg;
                    int j = wave * 32 + cj * 16 + l15;
                    float r = rcp_f(1.f + __expf(-aRZ[rt][cj][reg]));
                    float z = rcp_f(1.f + __expf(-aRZ[rt][2 + cj][reg]));
                    float ghn = aN[rt][cj][reg] + bhn[cj];
                    float tv = aNI[rt][cj][reg] + r * ghn;
                    float e2 = __expf(-2.f * tv);
                    float nv = 2.f * rcp_f(1.f + e2) - 1.f;   // tanh
                    float h = hm[rt][cj][reg];
                    float hn2 = nv + z * (h - nv);
                    hm[rt][cj][reg] = hn2;
                    unsigned short hbv = f2b(hn2);
                    htile[rl][j] = hbv;
                    size_t go = (size_t)(rb + rl) * HH + j;
                    if (ki == u0) hpred[go] = hbv;
                    if (ki == u1) hpred[(size_t)BB * HH + go] = hbv;
                }
        // next iteration's oh-build touches only oh[]; its barrier publishes htile writes
    }
}

// Fused 3-layer MLP: 128 blocks x 96 rows; single XOR-swizzled LDS tile,
// x2 overwrites x1 in place (acc lives in regs between barriers).
__device__ __forceinline__ int xsw(int row, int chunk) {
    return (row << 9) + ((chunk ^ (row & 7)) << 3);   // ushort index, 16B granules
}

__global__ void __launch_bounds__(512, 2)
k_mlp_all(const unsigned short* __restrict__ hpred, const unsigned short* __restrict__ w1t,
          const unsigned short* __restrict__ w2t, const unsigned short* __restrict__ w3t,
          const float* __restrict__ b1, const float* __restrict__ b2,
          const float* __restrict__ b3, float* __restrict__ pred) {
    __shared__ unsigned short xs[96 * 512];
    int tid = threadIdx.x, wave = tid >> 6, lane = tid & 63;
    int l15 = lane & 15, grp = lane >> 4, lk8 = grp << 3, r4 = grp << 2;
    int rb = blockIdx.x * 96;

    // Layer 1: x1 = relu(hpred @ W1 + b1), K=256, wave owns 64 cols
    {
        f32x4 acc[6][4] = {};
        for (int kk = 0; kk < 8; ++kk) {
            int k0 = kk * 32 + lk8;
            bf16x8 av[6];
#pragma unroll
            for (int rt = 0; rt < 6; ++rt)
                av[rt] = *reinterpret_cast<const bf16x8*>(&hpred[(size_t)(rb + rt * 16 + l15) * HH + k0]);
#pragma unroll
            for (int ct = 0; ct < 4; ++ct) {
                int col = wave * 64 + ct * 16 + l15;
                bf16x8 bv = *reinterpret_cast<const bf16x8*>(&w1t[(size_t)col * HH + k0]);
#pragma unroll
                for (int rt = 0; rt < 6; ++rt) acc[rt][ct] = mfma16(av[rt], bv, acc[rt][ct]);
            }
        }
#pragma unroll
        for (int ct = 0; ct < 4; ++ct) {
            int col = wave * 64 + ct * 16 + l15;
            float bb = b1[col];
#pragma unroll
            for (int rt = 0; rt < 6; ++rt)
#pragma unroll
                for (int reg = 0; reg < 4; ++reg) {
                    int row = rt * 16 + r4 + reg;
                    xs[xsw(row, col >> 3) + (col & 7)] = f2b(fmaxf(acc[rt][ct][reg] + bb, 0.f));
                }
        }
    }
    __syncthreads();

    // Layer 2: x2 = relu(x1 @ W2 + b2), K=512
    {
        f32x4 acc[6][4] = {};
        for (int kk = 0; kk < 16; ++kk) {
            bf16x8 av[6];
#pragma unroll
            for (int rt = 0; rt < 6; ++rt)
                av[rt] = *reinterpret_cast<const bf16x8*>(&xs[xsw(rt * 16 + l15, kk * 4 + grp)]);
#pragma unroll
            for (int ct = 0; ct < 4; ++ct) {
                int col = wave * 64 + ct * 16 + l15;
                bf16x8 bv = *reinterpret_cast<const bf16x8*>(&w2t[(size_t)col * MM + kk * 32 + lk8]);
#pragma unroll
                for (int rt = 0; rt < 6; ++rt) acc[rt][ct] = mfma16(av[rt], bv, acc[rt][ct]);
            }
        }
        __syncthreads();   // everyone done reading x1 before overwrite
#pragma unroll
        for (int ct = 0; ct < 4; ++ct) {
            int col = wave * 64 + ct * 16 + l15;
            float bb = b2[col];
#pragma unroll
            for (int rt = 0; rt < 6; ++rt)
#pragma unroll
                for (int reg = 0; reg < 4; ++reg) {
                    int row = rt * 16 + r4 + reg;
                    xs[xsw(row, col >> 3) + (col & 7)] = f2b(fmaxf(acc[rt][ct][reg] + bb, 0.f));
                }
        }
    }
    __syncthreads();

    // Layer 3: pred = x2 @ W3 + b3 (f32 out), K=512, wave owns 32 cols
    {
        f32x4 acc[6][2] = {};
        for (int kk = 0; kk < 16; ++kk) {
            bf16x8 av[6];
#pragma unroll
            for (int rt = 0; rt < 6; ++rt)
                av[rt] = *reinterpret_cast<const bf16x8*>(&xs[xsw(rt * 16 + l15, kk * 4 + grp)]);
#pragma unroll
            for (int ct = 0; ct < 2; ++ct) {
                int col = wave * 32 + ct * 16 + l15;
                bf16x8 bv = *reinterpret_cast<const bf16x8*>(&w3t[(size_t)col * MM + kk * 32 + lk8]);
#pragma unroll
                for (int rt = 0; rt < 6; ++rt) acc[rt][ct] = mfma16(av[rt], bv, acc[rt][ct]);
            }
        }
#pragma unroll
        for (int ct = 0; ct < 2; ++ct) {
            int col = wave * 32 + ct * 16 + l15;
            float bb = b3[col];
#pragma unroll
            for (int rt = 0; rt < 6; ++rt)
#pragma unroll
                for (int reg = 0; reg < 4; ++reg) {
                    int row = rt * 16 + r4 + reg;
                    pred[(size_t)(rb + row) * HH + col] = acc[rt][ct][reg] + bb;
                }
        }
    }
}

// Loss: per-row reg term + masked normalized MSE; deterministic two-stage reduce.
__global__ void k_loss(const float* __restrict__ pred, const float* __restrict__ z_t,
                       const float* __restrict__ dones, const int* __restrict__ ts,
                       const int* __restrict__ us, float* part) {
    int wave = threadIdx.x >> 6, lane = threadIdx.x & 63;
    float mse_l = 0.f;
    float cnt_l = 0.f, reg_l = 0.f;

    for (int i = 0; i < 3; ++i) {
        int row = blockIdx.x * 12 + wave * 3 + i;
        int f = row / BB, b = row - f * BB;
        int n = b / SS, s = b - n * SS;
        int t = ts[s], u = us[f];

        const float* pr = pred + (size_t)row * HH;
        float pv[4], ssq = 0.f;
#pragma unroll
        for (int q = 0; q < 4; ++q) { pv[q] = pr[lane + 64 * q]; ssq += pv[q] * pv[q]; }
        for (int o = 32; o; o >>= 1) ssq += __shfl_xor(ssq, o);
        float norm = sqrtf(ssq);
        if (lane == 0) { float d = norm - 1.f; reg_l += 0.02f * d * d; }

        bool valid = (t + u) < (TT - 1);
        if (valid) {
            float m = 1.f;
            for (int jj = 0; jj <= u; ++jj) m *= (1.f - dones[n * TT + t + jj]);
            valid = (m > 0.f);
        }
        if (!valid) continue;

        const float* zr = z_t + (size_t)(n * TT + 1 + t + u) * HH;
        float zv[4], zsq = 0.f;
#pragma unroll
        for (int q = 0; q < 4; ++q) { zv[q] = zr[lane + 64 * q]; zsq += zv[q] * zv[q]; }
        for (int o = 32; o; o >>= 1) zsq += __shfl_xor(zsq, o);
        float tn = sqrtf(zsq);

        float ip = 1.f / fmaxf(norm, 1e-8f);
        float it = 1.f / fmaxf(tn, 1e-8f);
        float e = 0.f;
#pragma unroll
        for (int q = 0; q < 4; ++q) { float d = pv[q] * ip - zv[q] * it; e += d * d; }
        mse_l += e * (1.f / HH);
        if (lane == 0) cnt_l += 1.f;
    }

    for (int o = 32; o; o >>= 1) mse_l += __shfl_xor(mse_l, o);

    __shared__ float sm[4][3];
    if (lane == 0) { sm[wave][0] = mse_l; sm[wave][1] = cnt_l; sm[wave][2] = reg_l; }
    __syncthreads();
    if (threadIdx.x == 0) {
        float s0 = 0.f, s1 = 0.f, s2 = 0.f;
        for (int w = 0; w < 4; ++w) { s0 += sm[w][0]; s1 += sm[w][1]; s2 += sm[w][2]; }
        part[blockIdx.x * 3 + 0] = s0;
        part[blockIdx.x * 3 + 1] = s1;
        part[blockIdx.x * 3 + 2] = s2;
    }
}

__global__ void k_final(const float* __restrict__ part, float* out) {
    int tid = threadIdx.x, wave = tid >> 6, lane = tid & 63;
    float s0 = 0.f, s1 = 0.f, s2 = 0.f;
    for (int i = tid; i < LOSS_BLOCKS; i += 256) {
        s0 += part[i * 3 + 0];
        s1 += part[i * 3 + 1];
        s2 += part[i * 3 + 2];
    }
    for (int o = 32; o; o >>= 1) {
        s0 += __shfl_xor(s0, o);
        s1 += __shfl_xor(s1, o);
        s2 += __shfl_xor(s2, o);
    }
    __shared__ float sm[4][3];
    if (lane == 0) { sm[wave][0] = s0; sm[wave][1] = s1; sm[wave][2] = s2; }
    __syncthreads();
    if (tid == 0) {
        float a = 0.f, b = 0.f, c = 0.f;
        for (int w = 0; w < 4; ++w) { a += sm[w][0]; b += sm[w][1]; c += sm[w][2]; }
        out[0] = a / fmaxf(b, 1.f) + c * (1.f / RR);
    }
}

extern "C" void kernel_launch(void* const* d_in, const int* in_sizes, int n_in,
                              void* d_out, int out_size, void* d_ws, size_t ws_size,
                              hipStream_t stream) {
    const int*   actions = (const int*)d_in[0];
    const float* dones   = (const float*)d_in[1];
    const float* b_t     = (const float*)d_in[2];
    const float* z_t     = (const float*)d_in[3];
    const int*   ts      = (const int*)d_in[4];
    const int*   us      = (const int*)d_in[5];
    const float* W_ih    = (const float*)d_in[6];
    const float* W_hh    = (const float*)d_in[7];
    const float* b_ih    = (const float*)d_in[8];
    const float* b_hh    = (const float*)d_in[9];
    const float* W1      = (const float*)d_in[10];
    const float* b1      = (const float*)d_in[11];
    const float* W2      = (const float*)d_in[12];
    const float* b2      = (const float*)d_in[13];
    const float* W3      = (const float*)d_in[14];
    const float* b3      = (const float*)d_in[15];

    char* ws = (char*)d_ws;
    int*            act   = (int*)(ws + OFF_ACT);
    unsigned short* hpred = (unsigned short*)(ws + OFF_HPRED);
    float*          pred  = (float*)(ws + OFF_PRED);
    unsigned short* whh_b = (unsigned short*)(ws + OFF_WHH);
    unsigned short* w1t   = (unsigned short*)(ws + OFF_W1T);
    unsigned short* w2t   = (unsigned short*)(ws + OFF_W2T);
    unsigned short* w3t   = (unsigned short*)(ws + OFF_W3T);
    unsigned short* wihp  = (unsigned short*)(ws + OFF_WIHP);
    float*          part  = (float*)(ws + OFF_PART);

    k_prep<<<3392, 256, 0, stream>>>(W_hh, W1, W2, W3, W_ih, b_ih, b_hh, actions, ts,
                                     whh_b, w1t, w2t, w3t, wihp, act);
    k_gru_all<<<128, 512, 0, stream>>>(whh_b, wihp, b_hh, act, us, ts, b_t, hpred);
    k_mlp_all<<<128, 512, 0, stream>>>(hpred, w1t, w2t, w3t, b1, b2, b3, pred);
    k_loss<<<LOSS_BLOCKS, 256, 0, stream>>>(pred, z_t, dones, ts, us, part);
    k_final<<<1, 256, 0, stream>>>(part, (float*)d_out);
}

// Round 4
// 114.046 us; speedup vs baseline: 6.6124x; 1.7295x over previous
//
#include <hip/hip_runtime.h>
#include <hip/hip_bf16.h>
#include <math.h>

// Problem constants (from setup_inputs):
#define NN 1024
#define TT 128
#define SS 6
#define FF 2
#define HH 256
#define AA 18
#define MM 512
#define KH 20
#define BB (NN*SS)        // 6144
#define RR (FF*BB)        // 12288
#define LOSS_BLOCKS 1024

#define SCL_RZ (-1.44269504089f)      // -log2(e): sigmoid(x)=rcp(1+exp2(-x*log2e))
#define SCL_N  (-2.88539008178f)      // -2*log2(e): tanh(x)=2*rcp(1+exp2(-2x*log2e))-1
#define TBL_STRIDE 784                // 768 + 16 pad (f32) -> +16 bank shift per action row

typedef __bf16 bf16x8 __attribute__((ext_vector_type(8)));
typedef float f32x4 __attribute__((ext_vector_type(4)));

__device__ __forceinline__ f32x4 mfma16(bf16x8 a, bf16x8 b, f32x4 c) {
    return __builtin_amdgcn_mfma_f32_16x16x32_bf16(a, b, c, 0, 0, 0);
}
__device__ __forceinline__ unsigned short f2b(float f) {
    return __builtin_bit_cast(unsigned short, __float2bfloat16(f));
}
__device__ __forceinline__ float rcp_f(float x)  { return __builtin_amdgcn_rcpf(x); }
__device__ __forceinline__ float exp2_f(float x) { return __builtin_amdgcn_exp2f(x); }

// ---- ws layout (bytes) ----
#define OFF_ACT   0UL                 // BB*20 int (act[b][k], values 0..18; 18 = padded step)
#define OFF_HPRED 491520UL            // RR*HH bf16  = 6,291,456
#define OFF_PRED  6782976UL           // RR*HH f32   = 12,582,912
#define OFF_WHH   19365888UL          // 768*256 bf16 (pre-scaled) = 393,216
#define OFF_W1T   19759104UL          // 512*256 bf16 = 262,144
#define OFF_W2T   20021248UL          // 512*512 bf16 = 524,288
#define OFF_W3T   20545536UL          // 256*512 bf16 = 262,144
#define OFF_TBL   20807680UL          // 19*784 f32 = 59,584 (gi lookup, biases+scale folded)
#define OFF_PART  20867264UL          // LOSS_BLOCKS*3 f32 = 12,288

// Prep: scaled bf16 W_hh, transposed MLP weights, gi lookup table, action table.
__global__ void k_prep(const float* __restrict__ Whh, const float* __restrict__ W1,
                       const float* __restrict__ W2, const float* __restrict__ W3,
                       const float* __restrict__ Wih, const float* __restrict__ bih,
                       const float* __restrict__ bhh,
                       const int* __restrict__ actions, const int* __restrict__ ts,
                       unsigned short* whh_s, unsigned short* w1t, unsigned short* w2t,
                       unsigned short* w3t, float* tbl, int* act) {
    int idx = blockIdx.x * 256 + threadIdx.x;
    if (idx < 196608) {   // W_hh, pre-scaled per gate
        int wrow = idx >> 8;
        float scl = (wrow < 512) ? SCL_RZ : SCL_N;
        whh_s[idx] = f2b(Whh[idx] * scl);
        return;
    }
    idx -= 196608;
    if (idx < 131072) { int m = idx >> 8, k = idx & 255; w1t[idx] = f2b(W1[k * MM + m]); return; }
    idx -= 131072;
    if (idx < 262144) { int m = idx >> 9, k = idx & 511; w2t[idx] = f2b(W2[k * MM + m]); return; }
    idx -= 262144;
    if (idx < 131072) { int c = idx >> 9, k = idx & 511; w3t[idx] = f2b(W3[k * HH + c]); return; }
    idx -= 131072;
    if (idx < 19 * TBL_STRIDE) {   // gi lookup: tbl[a][g*256+j] = scale_g*(Wih[g*256+j][a] + bih + (g<2)*bhh)
        int a = idx / TBL_STRIDE, rem = idx - a * TBL_STRIDE;
        float v = 0.f;
        if (rem < 768) {
            int g = rem >> 8;
            float scl = (g < 2) ? SCL_RZ : SCL_N;
            float w = (a < AA) ? Wih[rem * AA + a] : 0.f;
            v = scl * (w + bih[rem] + ((g < 2) ? bhh[rem] : 0.f));
        }
        tbl[idx] = v;
        return;
    }
    idx -= 19 * TBL_STRIDE;
    {   // act[b][k]: action index, AA(=18) for padded steps
        int b = idx / KH, k = idx - b * KH;
        int n = b / SS, s = b - n * SS;
        int tt = ts[s] + k;
        act[idx] = (tt < TT - 1) ? actions[n * TT + tt] : AA;
    }
}

// Persistent weights-stationary GRU: 384 blocks x 512 thr; block owns 16 rows.
// W_hh fully register-resident (48 bf16x8/lane); step loop touches LDS only.
__global__ void __launch_bounds__(512, 2)
k_gru_all(const unsigned short* __restrict__ whh_s, const float* __restrict__ tblg,
          const float* __restrict__ bhh, const int* __restrict__ actg,
          const int* __restrict__ us, const int* __restrict__ ts,
          const float* __restrict__ b_t, unsigned short* __restrict__ hpred) {
    __shared__ float tbl[19 * TBL_STRIDE];          // 59.6 KB
    __shared__ int act_l[16][KH];                   // 1.25 KB
    __shared__ unsigned short htile[16][264];       // 8.4 KB (+8 pad)

    int tid = threadIdx.x, wave = tid >> 6, lane = tid & 63;
    int l15 = lane & 15, grp = lane >> 4, lk8 = grp << 3, r4 = grp << 2;
    int rb = blockIdx.x * 16;
    int u0 = us[0], u1 = us[1];
    int kmax = u0 > u1 ? u0 : u1;

    // stage lookup table + actions to LDS
    for (int i = tid; i < 19 * TBL_STRIDE / 4; i += 512)
        reinterpret_cast<float4*>(tbl)[i] = reinterpret_cast<const float4*>(tblg)[i];
    if (tid < 16 * KH) {
        int r = tid / KH, k = tid - r * KH;
        act_l[r][k] = actg[(rb + r) * KH + k];
    }

    // weights -> registers: wave owns j-window [wave*32, wave*32+32), 3 gates.
    // ct: {0,1}=r(cj0,1) {2,3}=z {4,5}=n; B-frag col = l15 -> j = wave*32+(ct&1)*16+l15
    bf16x8 wr[6][8];
#pragma unroll
    for (int ct = 0; ct < 6; ++ct) {
        int wrow = (ct >> 1) * 256 + wave * 32 + (ct & 1) * 16 + l15;
        const unsigned short* base = &whh_s[(size_t)wrow * HH];
#pragma unroll
        for (int kk = 0; kk < 8; ++kk)
            wr[ct][kk] = *reinterpret_cast<const bf16x8*>(&base[kk * 32 + lk8]);
    }

    // fp32 h master: element (cj,reg) = (row r4+reg, col wave*32+cj*16+l15)
    float hm[2][4];
#pragma unroll
    for (int cj = 0; cj < 2; ++cj)
#pragma unroll
        for (int reg = 0; reg < 4; ++reg) {
            int b = rb + r4 + reg;
            int n = b / SS, s = b - n * SS;
            hm[cj][reg] = b_t[(size_t)(n * TT + ts[s]) * HH + wave * 32 + cj * 16 + l15];
        }
    float bhn[2];
#pragma unroll
    for (int cj = 0; cj < 2; ++cj) bhn[cj] = SCL_N * bhh[512 + wave * 32 + cj * 16 + l15];

    // initial htile = bf16(h0): one 8-col chunk per thread
    {
        int row = tid >> 5, c8 = (tid & 31) << 3;
        int b = rb + row;
        int n = b / SS, s = b - n * SS;
        const float* src = &b_t[(size_t)(n * TT + ts[s]) * HH + c8];
        uint4 pk;
        pk.x = f2b(src[0]) | ((unsigned)f2b(src[1]) << 16);
        pk.y = f2b(src[2]) | ((unsigned)f2b(src[3]) << 16);
        pk.z = f2b(src[4]) | ((unsigned)f2b(src[5]) << 16);
        pk.w = f2b(src[6]) | ((unsigned)f2b(src[7]) << 16);
        *reinterpret_cast<uint4*>(&htile[row][c8]) = pk;
    }
    __syncthreads();

    for (int ki = 0; ki <= kmax; ++ki) {
        // gh = h @ Whh_scaled^T : all operands in regs/LDS
        f32x4 aR[2] = {}, aZ[2] = {}, aN[2] = {};
#pragma unroll
        for (int kk = 0; kk < 8; ++kk) {
            bf16x8 ah = *reinterpret_cast<const bf16x8*>(&htile[l15][kk * 32 + lk8]);
            aR[0] = mfma16(ah, wr[0][kk], aR[0]);
            aR[1] = mfma16(ah, wr[1][kk], aR[1]);
            aZ[0] = mfma16(ah, wr[2][kk], aZ[0]);
            aZ[1] = mfma16(ah, wr[3][kk], aZ[1]);
            aN[0] = mfma16(ah, wr[4][kk], aN[0]);
            aN[1] = mfma16(ah, wr[5][kk], aN[1]);
        }
        __syncthreads();   // all htile reads done

        // gates + update; gi via LDS lookup (biases + exp2-scale pre-folded)
#pragma unroll
        for (int cj = 0; cj < 2; ++cj) {
            int j2 = wave * 32 + cj * 16 + l15;
            float bhnv = bhn[cj];
#pragma unroll
            for (int reg = 0; reg < 4; ++reg) {
                int row = r4 + reg;
                const float* tb = &tbl[act_l[row][ki] * TBL_STRIDE];
                float r = rcp_f(1.f + exp2_f(aR[cj][reg] + tb[j2]));
                float z = rcp_f(1.f + exp2_f(aZ[cj][reg] + tb[256 + j2]));
                float ghn = aN[cj][reg] + bhnv;
                float nv = 2.f * rcp_f(1.f + exp2_f(tb[512 + j2] + r * ghn)) - 1.f;
                float h = hm[cj][reg];
                float hn2 = nv + z * (h - nv);
                hm[cj][reg] = hn2;
                unsigned short hbv = f2b(hn2);
                htile[row][j2] = hbv;
                if (ki == u0) hpred[(size_t)(rb + row) * HH + j2] = hbv;
                if (ki == u1) hpred[(size_t)(BB + rb + row) * HH + j2] = hbv;
            }
        }
        __syncthreads();   // htile writes visible before next step's reads
    }
}

// Fused 3-layer MLP: 256 blocks x 48 rows; XOR-swizzled LDS tile reused across layers.
__device__ __forceinline__ int xsw(int row, int chunk) {
    return (row << 9) + ((chunk ^ (row & 7)) << 3);   // ushort index, 16B granules
}

__global__ void __launch_bounds__(512, 2)
k_mlp_all(const unsigned short* __restrict__ hpred, const unsigned short* __restrict__ w1t,
          const unsigned short* __restrict__ w2t, const unsigned short* __restrict__ w3t,
          const float* __restrict__ b1, const float* __restrict__ b2,
          const float* __restrict__ b3, float* __restrict__ pred) {
    __shared__ unsigned short xs[48 * 512];   // 49 KB
    int tid = threadIdx.x, wave = tid >> 6, lane = tid & 63;
    int l15 = lane & 15, grp = lane >> 4, lk8 = grp << 3, r4 = grp << 2;
    int rb = blockIdx.x * 48;

    // Layer 1: x1 = relu(hpred @ W1 + b1), K=256, wave owns 64 cols
    {
        f32x4 acc[3][4] = {};
        for (int kk = 0; kk < 8; ++kk) {
            int k0 = kk * 32 + lk8;
            bf16x8 av[3];
#pragma unroll
            for (int rt = 0; rt < 3; ++rt)
                av[rt] = *reinterpret_cast<const bf16x8*>(&hpred[(size_t)(rb + rt * 16 + l15) * HH + k0]);
#pragma unroll
            for (int ct = 0; ct < 4; ++ct) {
                int col = wave * 64 + ct * 16 + l15;
                bf16x8 bv = *reinterpret_cast<const bf16x8*>(&w1t[(size_t)col * HH + k0]);
#pragma unroll
                for (int rt = 0; rt < 3; ++rt) acc[rt][ct] = mfma16(av[rt], bv, acc[rt][ct]);
            }
        }
#pragma unroll
        for (int ct = 0; ct < 4; ++ct) {
            int col = wave * 64 + ct * 16 + l15;
            float bb = b1[col];
#pragma unroll
            for (int rt = 0; rt < 3; ++rt)
#pragma unroll
                for (int reg = 0; reg < 4; ++reg) {
                    int row = rt * 16 + r4 + reg;
                    xs[xsw(row, col >> 3) + (col & 7)] = f2b(fmaxf(acc[rt][ct][reg] + bb, 0.f));
                }
        }
    }
    __syncthreads();

    // Layer 2: x2 = relu(x1 @ W2 + b2), K=512
    {
        f32x4 acc[3][4] = {};
        for (int kk = 0; kk < 16; ++kk) {
            bf16x8 av[3];
#pragma unroll
            for (int rt = 0; rt < 3; ++rt)
                av[rt] = *reinterpret_cast<const bf16x8*>(&xs[xsw(rt * 16 + l15, kk * 4 + grp)]);
#pragma unroll
            for (int ct = 0; ct < 4; ++ct) {
                int col = wave * 64 + ct * 16 + l15;
                bf16x8 bv = *reinterpret_cast<const bf16x8*>(&w2t[(size_t)col * MM + kk * 32 + lk8]);
#pragma unroll
                for (int rt = 0; rt < 3; ++rt) acc[rt][ct] = mfma16(av[rt], bv, acc[rt][ct]);
            }
        }
        __syncthreads();   // everyone done reading x1 before overwrite
#pragma unroll
        for (int ct = 0; ct < 4; ++ct) {
            int col = wave * 64 + ct * 16 + l15;
            float bb = b2[col];
#pragma unroll
            for (int rt = 0; rt < 3; ++rt)
#pragma unroll
                for (int reg = 0; reg < 4; ++reg) {
                    int row = rt * 16 + r4 + reg;
                    xs[xsw(row, col >> 3) + (col & 7)] = f2b(fmaxf(acc[rt][ct][reg] + bb, 0.f));
                }
        }
    }
    __syncthreads();

    // Layer 3: pred = x2 @ W3 + b3 (f32 out), K=512, wave owns 32 cols
    {
        f32x4 acc[3][2] = {};
        for (int kk = 0; kk < 16; ++kk) {
            bf16x8 av[3];
#pragma unroll
            for (int rt = 0; rt < 3; ++rt)
                av[rt] = *reinterpret_cast<const bf16x8*>(&xs[xsw(rt * 16 + l15, kk * 4 + grp)]);
#pragma unroll
            for (int ct = 0; ct < 2; ++ct) {
                int col = wave * 32 + ct * 16 + l15;
                bf16x8 bv = *reinterpret_cast<const bf16x8*>(&w3t[(size_t)col * MM + kk * 32 + lk8]);
#pragma unroll
                for (int rt = 0; rt < 3; ++rt) acc[rt][ct] = mfma16(av[rt], bv, acc[rt][ct]);
            }
        }
#pragma unroll
        for (int ct = 0; ct < 2; ++ct) {
            int col = wave * 32 + ct * 16 + l15;
            float bb = b3[col];
#pragma unroll
            for (int rt = 0; rt < 3; ++rt)
#pragma unroll
                for (int reg = 0; reg < 4; ++reg) {
                    int row = rt * 16 + r4 + reg;
                    pred[(size_t)(rb + row) * HH + col] = acc[rt][ct][reg] + bb;
                }
        }
    }
}

// Loss: per-row reg term + masked normalized MSE; deterministic two-stage reduce.
__global__ void k_loss(const float* __restrict__ pred, const float* __restrict__ z_t,
                       const float* __restrict__ dones, const int* __restrict__ ts,
                       const int* __restrict__ us, float* part) {
    int wave = threadIdx.x >> 6, lane = threadIdx.x & 63;
    float mse_l = 0.f;
    float cnt_l = 0.f, reg_l = 0.f;

    for (int i = 0; i < 3; ++i) {
        int row = blockIdx.x * 12 + wave * 3 + i;
        int f = row / BB, b = row - f * BB;
        int n = b / SS, s = b - n * SS;
        int t = ts[s], u = us[f];

        const float* pr = pred + (size_t)row * HH;
        float pv[4], ssq = 0.f;
#pragma unroll
        for (int q = 0; q < 4; ++q) { pv[q] = pr[lane + 64 * q]; ssq += pv[q] * pv[q]; }
        for (int o = 32; o; o >>= 1) ssq += __shfl_xor(ssq, o);
        float norm = sqrtf(ssq);
        if (lane == 0) { float d = norm - 1.f; reg_l += 0.02f * d * d; }

        bool valid = (t + u) < (TT - 1);
        if (valid) {
            float m = 1.f;
            for (int jj = 0; jj <= u; ++jj) m *= (1.f - dones[n * TT + t + jj]);
            valid = (m > 0.f);
        }
        if (!valid) continue;

        const float* zr = z_t + (size_t)(n * TT + 1 + t + u) * HH;
        float zv[4], zsq = 0.f;
#pragma unroll
        for (int q = 0; q < 4; ++q) { zv[q] = zr[lane + 64 * q]; zsq += zv[q] * zv[q]; }
        for (int o = 32; o; o >>= 1) zsq += __shfl_xor(zsq, o);
        float tn = sqrtf(zsq);

        float ip = 1.f / fmaxf(norm, 1e-8f);
        float it = 1.f / fmaxf(tn, 1e-8f);
        float e = 0.f;
#pragma unroll
        for (int q = 0; q < 4; ++q) { float d = pv[q] * ip - zv[q] * it; e += d * d; }
        mse_l += e * (1.f / HH);
        if (lane == 0) cnt_l += 1.f;
    }

    for (int o = 32; o; o >>= 1) mse_l += __shfl_xor(mse_l, o);

    __shared__ float sm[4][3];
    if (lane == 0) { sm[wave][0] = mse_l; sm[wave][1] = cnt_l; sm[wave][2] = reg_l; }
    __syncthreads();
    if (threadIdx.x == 0) {
        float s0 = 0.f, s1 = 0.f, s2 = 0.f;
        for (int w = 0; w < 4; ++w) { s0 += sm[w][0]; s1 += sm[w][1]; s2 += sm[w][2]; }
        part[blockIdx.x * 3 + 0] = s0;
        part[blockIdx.x * 3 + 1] = s1;
        part[blockIdx.x * 3 + 2] = s2;
    }
}

__global__ void k_final(const float* __restrict__ part, float* out) {
    int tid = threadIdx.x, wave = tid >> 6, lane = tid & 63;
    float s0 = 0.f, s1 = 0.f, s2 = 0.f;
    for (int i = tid; i < LOSS_BLOCKS; i += 256) {
        s0 += part[i * 3 + 0];
        s1 += part[i * 3 + 1];
        s2 += part[i * 3 + 2];
    }
    for (int o = 32; o; o >>= 1) {
        s0 += __shfl_xor(s0, o);
        s1 += __shfl_xor(s1, o);
        s2 += __shfl_xor(s2, o);
    }
    __shared__ float sm[4][3];
    if (lane == 0) { sm[wave][0] = s0; sm[wave][1] = s1; sm[wave][2] = s2; }
    __syncthreads();
    if (tid == 0) {
        float a = 0.f, b = 0.f, c = 0.f;
        for (int w = 0; w < 4; ++w) { a += sm[w][0]; b += sm[w][1]; c += sm[w][2]; }
        out[0] = a / fmaxf(b, 1.f) + c * (1.f / RR);
    }
}

extern "C" void kernel_launch(void* const* d_in, const int* in_sizes, int n_in,
                              void* d_out, int out_size, void* d_ws, size_t ws_size,
                              hipStream_t stream) {
    const int*   actions = (const int*)d_in[0];
    const float* dones   = (const float*)d_in[1];
    const float* b_t     = (const float*)d_in[2];
    const float* z_t     = (const float*)d_in[3];
    const int*   ts      = (const int*)d_in[4];
    const int*   us      = (const int*)d_in[5];
    const float* W_ih    = (const float*)d_in[6];
    const float* W_hh    = (const float*)d_in[7];
    const float* b_ih    = (const float*)d_in[8];
    const float* b_hh    = (const float*)d_in[9];
    const float* W1      = (const float*)d_in[10];
    const float* b1      = (const float*)d_in[11];
    const float* W2      = (const float*)d_in[12];
    const float* b2      = (const float*)d_in[13];
    const float* W3      = (const float*)d_in[14];
    const float* b3      = (const float*)d_in[15];

    char* ws = (char*)d_ws;
    int*            act   = (int*)(ws + OFF_ACT);
    unsigned short* hpred = (unsigned short*)(ws + OFF_HPRED);
    float*          pred  = (float*)(ws + OFF_PRED);
    unsigned short* whh_s = (unsigned short*)(ws + OFF_WHH);
    unsigned short* w1t   = (unsigned short*)(ws + OFF_W1T);
    unsigned short* w2t   = (unsigned short*)(ws + OFF_W2T);
    unsigned short* w3t   = (unsigned short*)(ws + OFF_W3T);
    float*          tbl   = (float*)(ws + OFF_TBL);
    float*          part  = (float*)(ws + OFF_PART);

    // total prep elements: 196608+131072+262144+131072+14896+122880 = 858672
    k_prep<<<3355, 256, 0, stream>>>(W_hh, W1, W2, W3, W_ih, b_ih, b_hh, actions, ts,
                                     whh_s, w1t, w2t, w3t, tbl, act);
    k_gru_all<<<384, 512, 0, stream>>>(whh_s, tbl, b_hh, act, us, ts, b_t, hpred);
    k_mlp_all<<<256, 512, 0, stream>>>(hpred, w1t, w2t, w3t, b1, b2, b3, pred);
    k_loss<<<LOSS_BLOCKS, 256, 0, stream>>>(pred, z_t, dones, ts, us, part);
    k_final<<<1, 256, 0, stream>>>(part, (float*)d_out);
}